// Round 2
// baseline (382.069 us; speedup 1.0000x reference)
//
#include <hip/hip_runtime.h>

// BasicNCA: 16 sequential steps of (11x11 SAME conv -> per-pixel MLP 1->10->10->1
// -> residual -> clip[0,1]) on (16,1,256,256) fp32.
// out = 17 slabs (x, then 16 steps); step k reads slab k, writes slab k+1.
//
// R2 changes vs R1 (theory: s_load storm + staging round-trips + LDS pipe):
//  - MLP loop-interchanged: each weight s_load once/thread, reused for 8 px
//  - float4 staging from 16B-aligned 80-col halo superset (no scalar round-trips)
//  - 8 px/thread (64x32 tile): 6 ds_read_b128 per ky per 8 px (0.75/px)
//  - residual xc taken from ky==5 window registers

#define HH 256
#define WW 256
#define BB 16
#define TH 32
#define TW 64
#define SH (TH + 10)   // 42 staged rows
#define SW 80          // staged cols: gx0-8 .. gx0+71 (16B-aligned superset of halo)
#define SLAB (BB * HH * WW)

__global__ __launch_bounds__(256) void nca_copy_x(const float* __restrict__ x,
                                                  float* __restrict__ out) {
    int i = (blockIdx.x * 256 + threadIdx.x) * 4;
    *(float4*)(out + i) = *(const float4*)(x + i);
}

__global__ __launch_bounds__(256) void nca_step(
    const float* __restrict__ src, float* __restrict__ dst,
    const float* __restrict__ Kk,
    const float* __restrict__ w1, const float* __restrict__ b1,
    const float* __restrict__ w2, const float* __restrict__ b2,
    const float* __restrict__ w3, const float* __restrict__ b3) {
    __shared__ __align__(16) float s[SH * SW];

    const int tid = threadIdx.x;
    const int b   = blockIdx.z;
    const int gy0 = blockIdx.y * TH;
    const int gx0 = blockIdx.x * TW;
    const float* img = src + b * HH * WW;

    // ---- stage 42 rows x 20 float4-cols; every float4 is fully in-image or fully out ----
    for (int t = tid; t < SH * (SW / 4); t += 256) {
        int r = t / (SW / 4), c = t - r * (SW / 4);
        int gy = gy0 - 5 + r;
        int gx = gx0 - 8 + c * 4;
        float4 v = make_float4(0.f, 0.f, 0.f, 0.f);
        if ((unsigned)gy < HH && (unsigned)gx < WW)
            v = *(const float4*)(img + gy * WW + gx);
        *(float4*)(s + r * SW + c * 4) = v;
    }
    __syncthreads();

    const int tx = tid & 7, ty = tid >> 3;
    const int x0 = tx * 8;  // 8 output pixels per thread
    // output px (x0+p) at staged col (x0+p+3)..(x0+p+13); window regs cover [x0, x0+24)

    float acc[8] = {0, 0, 0, 0, 0, 0, 0, 0};
    float xc[8];
#pragma unroll
    for (int ky = 0; ky < 11; ++ky) {
        const float* row = &s[(ty + ky) * SW + x0];
        float win[24];
        *(float4*)(win + 0)  = *(const float4*)(row + 0);
        *(float4*)(win + 4)  = *(const float4*)(row + 4);
        *(float4*)(win + 8)  = *(const float4*)(row + 8);
        *(float4*)(win + 12) = *(const float4*)(row + 12);
        *(float4*)(win + 16) = *(const float4*)(row + 16);
        *(float4*)(win + 20) = *(const float4*)(row + 20);
        if (ky == 5) {
#pragma unroll
            for (int p = 0; p < 8; ++p) xc[p] = win[p + 8];  // center = residual input
        }
        const float* krow = Kk + ky * 11;
        float kr[11];
#pragma unroll
        for (int j = 0; j < 11; ++j) kr[j] = krow[j];  // uniform -> merged s_loads
#pragma unroll
        for (int kx = 0; kx < 11; ++kx) {
#pragma unroll
            for (int p = 0; p < 8; ++p)
                acc[p] = fmaf(win[kx + p + 3], kr[kx], acc[p]);
        }
    }

    // ---- MLP 1->10->10->1, loop-interchanged: each weight loaded once, used 4 px ----
    const float b3v = b3[0];
    float res[8];
#pragma unroll
    for (int g = 0; g < 2; ++g) {
        float h1[4][10];
#pragma unroll
        for (int i = 0; i < 10; ++i) {
            float w1i = w1[i], b1i = b1[i];
#pragma unroll
            for (int p = 0; p < 4; ++p)
                h1[p][i] = fmaxf(fmaf(acc[g * 4 + p], w1i, b1i), 0.f);
        }
        float yv[4] = {b3v, b3v, b3v, b3v};
#pragma unroll
        for (int o = 0; o < 10; ++o) {
            float b2o = b2[o];
            float a[4] = {b2o, b2o, b2o, b2o};
#pragma unroll
            for (int i = 0; i < 10; ++i) {
                float w = w2[o * 10 + i];
#pragma unroll
                for (int p = 0; p < 4; ++p)
                    a[p] = fmaf(h1[p][i], w, a[p]);
            }
            float w3o = w3[o];
#pragma unroll
            for (int p = 0; p < 4; ++p)
                yv[p] = fmaf(fmaxf(a[p], 0.f), w3o, yv[p]);
        }
#pragma unroll
        for (int p = 0; p < 4; ++p)
            res[g * 4 + p] = fminf(fmaxf(xc[g * 4 + p] + yv[p], 0.f), 1.f);
    }

    float* orow = dst + b * HH * WW + (gy0 + ty) * WW + gx0 + x0;
    *(float4*)(orow + 0) = *(float4*)(res + 0);
    *(float4*)(orow + 4) = *(float4*)(res + 4);
}

extern "C" void kernel_launch(void* const* d_in, const int* in_sizes, int n_in,
                              void* d_out, int out_size, void* d_ws, size_t ws_size,
                              hipStream_t stream) {
    const float* x  = (const float*)d_in[0];
    const float* Kk = (const float*)d_in[1];
    const float* w1 = (const float*)d_in[2];
    const float* b1 = (const float*)d_in[3];
    const float* w2 = (const float*)d_in[4];
    const float* b2 = (const float*)d_in[5];
    const float* w3 = (const float*)d_in[6];
    const float* b3 = (const float*)d_in[7];
    float* out = (float*)d_out;

    nca_copy_x<<<SLAB / (256 * 4), 256, 0, stream>>>(x, out);

    dim3 grid(WW / TW, HH / TH, BB);  // 4 x 8 x 16 = 512 blocks, 2 blocks/CU
    for (int k = 0; k < 16; ++k) {
        nca_step<<<grid, 256, 0, stream>>>(out + (size_t)k * SLAB,
                                           out + (size_t)(k + 1) * SLAB,
                                           Kk, w1, b1, w2, b2, w3, b3);
    }
}